// Round 1
// baseline (669.823 us; speedup 1.0000x reference)
//
#include <hip/hip_runtime.h>
#include <hip/hip_bf16.h>
#include <math.h>

// TriangleMultiplicativeUpdate (outgoing), B=1 N=512 C_Z=C_H=128, fp32 in/out.
// R2: k_proj_fused latency-bound rewrite:
//   - LN affine folded into weights (k_wt_all: W'=g⊙W) and biases (k_bias: b'=b+b_ln@W)
//     -> LN phase stores plain (x-mean)*rsqrt, no g/b loads/FMAs anywhere.
//   - LN reduce: 4 lanes/row * 32 contiguous elems -> 2 shfl_xor pairs (was 16x6).
//   - Per-wave transpose staging (16ch x 64row, private per wave) -> 3 barriers (was 7).
//   - LDS 35840 -> 26624 B: 6 blocks/CU eligible (was 4).
//   - nt-split MFMA halves weight+acc register pressure.
// k_tri: register prefetch of next K-slab before MFMA (latency under compute) +
//        bijective XCD-grouping swizzle (one channel's 16 tiles share an XCD L2).
// k_out: ln_out folded into wz_t/bz' (k_wt_all/k_bias).

#define N 512
#define C 128
#define NN (N*N)
#define PK 136   // padded LDS stride (u16) for MFMA A tiles
#define PT 40    // padded LDS stride for K=32 bf16 tiles (k_tri)
#define PX 137   // padded LDS stride for fp32 x-tile transpose (k_out)
#define ST 72    // per-channel stride (u16) in per-wave transpose buffer

typedef __attribute__((ext_vector_type(8))) short bf16x8;
typedef __attribute__((ext_vector_type(4))) float f32x4;
typedef unsigned short u16;
typedef unsigned int u32;

__device__ __forceinline__ u16 f2bf(float f) {
    u32 u = __builtin_bit_cast(u32, f);
    u = (u + 0x7fffu + ((u >> 16) & 1u)) >> 16;
    return (u16)u;
}
__device__ __forceinline__ float bf2f(u16 h) {
    return __builtin_bit_cast(float, ((u32)h) << 16);
}
__device__ __forceinline__ float sigmoidf(float x) {
    return 1.f / (1.f + __expf(-x));
}

// ------- K0: weights fp32 [in][out] -> bf16 transposed, LN gain folded in ----
__global__ __launch_bounds__(256) void k_wt_all(
    const float* __restrict__ w0, const float* __restrict__ w1,
    const float* __restrict__ w2, const float* __restrict__ w3,
    const float* __restrict__ w4, const float* __restrict__ w5,
    const float* __restrict__ gin, const float* __restrict__ gout,
    u16* __restrict__ o0, u16* __restrict__ o1, u16* __restrict__ o2,
    u16* __restrict__ o3, u16* __restrict__ o4, u16* __restrict__ o5) {
    int sel = blockIdx.x >> 6;
    int idx = (blockIdx.x & 63) * 256 + threadIdx.x;
    const float* w = sel == 0 ? w0 : sel == 1 ? w1 : sel == 2 ? w2
                   : sel == 3 ? w3 : sel == 4 ? w4 : w5;
    u16* o = sel == 0 ? o0 : sel == 1 ? o1 : sel == 2 ? o2
           : sel == 3 ? o3 : sel == 4 ? o4 : o5;
    const float* g = (sel == 5) ? gout : gin;
    int co = idx >> 7, k = idx & 127;
    o[idx] = f2bf(g[k] * w[k * C + co]);
}

// ------- K0b: adjusted biases  b'[c] = b[c] + sum_k b_ln[k]*W[k][c] ----------
__global__ __launch_bounds__(256) void k_bias(
    const float* __restrict__ w0, const float* __restrict__ w1,
    const float* __restrict__ w2, const float* __restrict__ w3,
    const float* __restrict__ w4, const float* __restrict__ w5,
    const float* __restrict__ b0, const float* __restrict__ b1,
    const float* __restrict__ b2, const float* __restrict__ b3,
    const float* __restrict__ b4, const float* __restrict__ b5,
    const float* __restrict__ vin, const float* __restrict__ vout,
    float* __restrict__ obias) {
    int id = blockIdx.x * 256 + threadIdx.x;   // 0..767
    int m = id >> 7, cc = id & 127;
    const float* w = m == 0 ? w0 : m == 1 ? w1 : m == 2 ? w2
                   : m == 3 ? w3 : m == 4 ? w4 : w5;
    const float* b = m == 0 ? b0 : m == 1 ? b1 : m == 2 ? b2
                   : m == 3 ? b3 : m == 4 ? b4 : b5;
    const float* v = (m == 5) ? vout : vin;
    float acc = 0.f;
#pragma unroll 4
    for (int k = 0; k < 128; ++k) acc += v[k] * w[k * C + cc];
    obias[id] = b[cc] + acc;
}

// ------- fused: LN(z) + a/b/gate projections ---------------------------------
// block = 256 threads, 64 rows. Wave w owns output cols [w*32, w*32+32).
__global__ __launch_bounds__(256) void k_proj_fused(
    const float* __restrict__ z, const float* __restrict__ mask,
    const u16* __restrict__ wag, const u16* __restrict__ wap,
    const u16* __restrict__ wbg, const u16* __restrict__ wbp,
    const u16* __restrict__ wgg, const float* __restrict__ biasAll,
    u16* __restrict__ aT, u16* __restrict__ bT, u16* __restrict__ gate) {
    __shared__ u16 sA[64 * PK];        // 17408 B
    __shared__ u16 sT[4][16 * ST];     //  9216 B, per-wave private 16ch x 64row
    long r0 = (long)blockIdx.x * 64;
    int tid = threadIdx.x, wave = tid >> 6, lane = tid & 63;
    int lo = lane & 15, quad = lane >> 4;

    // --- LN(z) -> sA (plain normalized, affine folded into weights/biases) ---
    {
        int rl = lane >> 2, cb = lane & 3;
        int row = wave * 16 + rl;
        const float* zr = z + (r0 + row) * C + cb * 32;
        float4 v[8];
        float s = 0.f, s2 = 0.f;
#pragma unroll
        for (int i = 0; i < 8; ++i) {
            v[i] = *(const float4*)(zr + i * 4);
            s  += v[i].x + v[i].y + v[i].z + v[i].w;
            s2 += v[i].x * v[i].x + v[i].y * v[i].y + v[i].z * v[i].z + v[i].w * v[i].w;
        }
        s += __shfl_xor(s, 1); s2 += __shfl_xor(s2, 1);
        s += __shfl_xor(s, 2); s2 += __shfl_xor(s2, 2);
        float mean = s * (1.f / 128.f);
        float rs = rsqrtf(s2 * (1.f / 128.f) - mean * mean + 1e-5f);
        u16* dst = &sA[row * PK + cb * 32];
#pragma unroll
        for (int j = 0; j < 4; ++j) {
            uint4 pk;
            pk.x = (u32)f2bf((v[2*j].x   - mean) * rs) | ((u32)f2bf((v[2*j].y   - mean) * rs) << 16);
            pk.y = (u32)f2bf((v[2*j].z   - mean) * rs) | ((u32)f2bf((v[2*j].w   - mean) * rs) << 16);
            pk.z = (u32)f2bf((v[2*j+1].x - mean) * rs) | ((u32)f2bf((v[2*j+1].y - mean) * rs) << 16);
            pk.w = (u32)f2bf((v[2*j+1].z - mean) * rs) | ((u32)f2bf((v[2*j+1].w - mean) * rs) << 16);
            *(uint4*)(dst + 8 * j) = pk;
        }
    }
    __syncthreads();

    int c0 = wave * 32;
    float msk[4][4];
#pragma unroll
    for (int mi = 0; mi < 4; ++mi)
#pragma unroll
        for (int r = 0; r < 4; ++r)
            msk[mi][r] = mask[r0 + mi * 16 + quad * 4 + r];

    u16* sTw = &sT[wave][0];

    // --- gated pair: outT[c][r] = mask*sigmoid(zn@wG+bG')*(zn@wP+bP') --------
    auto pair_stage = [&](const u16* __restrict__ wG, const float* __restrict__ bG,
                          const u16* __restrict__ wP, const float* __restrict__ bP,
                          u16* __restrict__ outT) {
#pragma unroll
        for (int nt = 0; nt < 2; ++nt) {
            int c = c0 + nt * 16 + lo;
            bf16x8 fG[4], fP[4];
#pragma unroll
            for (int ki = 0; ki < 4; ++ki) {
                fG[ki] = *(const bf16x8*)(wG + c * C + ki * 32 + quad * 8);
                fP[ki] = *(const bf16x8*)(wP + c * C + ki * 32 + quad * 8);
            }
            f32x4 aG[4], aP[4];
#pragma unroll
            for (int mi = 0; mi < 4; ++mi) { aG[mi] = (f32x4)(0.f); aP[mi] = (f32x4)(0.f); }
#pragma unroll
            for (int mi = 0; mi < 4; ++mi)
#pragma unroll
                for (int ki = 0; ki < 4; ++ki) {
                    bf16x8 av = *(const bf16x8*)(&sA[(mi * 16 + lo) * PK + ki * 32 + quad * 8]);
                    aG[mi] = __builtin_amdgcn_mfma_f32_16x16x32_bf16(av, fG[ki], aG[mi], 0, 0, 0);
                    aP[mi] = __builtin_amdgcn_mfma_f32_16x16x32_bf16(av, fP[ki], aP[mi], 0, 0, 0);
                }
            float bGv = bG[c], bPv = bP[c];
#pragma unroll
            for (int mi = 0; mi < 4; ++mi) {
                float v0 = msk[mi][0] * sigmoidf(aG[mi][0] + bGv) * (aP[mi][0] + bPv);
                float v1 = msk[mi][1] * sigmoidf(aG[mi][1] + bGv) * (aP[mi][1] + bPv);
                float v2 = msk[mi][2] * sigmoidf(aG[mi][2] + bGv) * (aP[mi][2] + bPv);
                float v3 = msk[mi][3] * sigmoidf(aG[mi][3] + bGv) * (aP[mi][3] + bPv);
                uint2 pk;
                pk.x = (u32)f2bf(v0) | ((u32)f2bf(v1) << 16);
                pk.y = (u32)f2bf(v2) | ((u32)f2bf(v3) << 16);
                *(uint2*)(&sTw[lo * ST + mi * 16 + quad * 4]) = pk;  // ch=lo, rows mi*16+quad*4..+3
            }
            // per-wave copy out: 16 ch x 64 rows, no barrier needed (wave-private)
            {
                int cl = lane >> 2, pr = lane & 3;
                uint4 x0 = *(const uint4*)(&sTw[cl * ST + pr * 16]);
                uint4 x1 = *(const uint4*)(&sTw[cl * ST + pr * 16 + 8]);
                u16* g = outT + (long)(c0 + nt * 16 + cl) * NN + r0 + pr * 16;
                *(uint4*)(g) = x0;
                *(uint4*)(g + 8) = x1;
            }
        }
    };
    pair_stage(wag, biasAll + 0,   wap, biasAll + 128, aT);
    pair_stage(wbg, biasAll + 256, wbp, biasAll + 384, bT);

    // --- gate: gate[r][c] = sigmoid(zn@w_g + b_g') ---------------------------
    {
        f32x4 gA[2][4];
#pragma unroll
        for (int nt = 0; nt < 2; ++nt) {
            bf16x8 gF[4];
#pragma unroll
            for (int ki = 0; ki < 4; ++ki)
                gF[ki] = *(const bf16x8*)(wgg + (c0 + nt * 16 + lo) * C + ki * 32 + quad * 8);
#pragma unroll
            for (int mi = 0; mi < 4; ++mi) gA[nt][mi] = (f32x4)(0.f);
#pragma unroll
            for (int mi = 0; mi < 4; ++mi)
#pragma unroll
                for (int ki = 0; ki < 4; ++ki) {
                    bf16x8 av = *(const bf16x8*)(&sA[(mi * 16 + lo) * PK + ki * 32 + quad * 8]);
                    gA[nt][mi] = __builtin_amdgcn_mfma_f32_16x16x32_bf16(av, gF[ki], gA[nt][mi], 0, 0, 0);
                }
        }
        __syncthreads();   // all waves done reading sA before overwrite
        const float* bg5 = biasAll + 512;
#pragma unroll
        for (int nt = 0; nt < 2; ++nt) {
            int c = c0 + nt * 16 + lo;
            float bv = bg5[c];
#pragma unroll
            for (int mi = 0; mi < 4; ++mi)
#pragma unroll
                for (int r = 0; r < 4; ++r)
                    sA[(mi * 16 + quad * 4 + r) * PK + c] = f2bf(sigmoidf(gA[nt][mi][r] + bv));
        }
        __syncthreads();
#pragma unroll
        for (int p = 0; p < 4; ++p) {
            int linear = p * 2048 + tid * 8;
            int row = linear >> 7, k = linear & 127;
            *(uint4*)(gate + (r0 + row) * C + k) = *(const uint4*)(&sA[row * PK + k]);
        }
    }
}

// ------- K3: per-channel 512x512x512 BT-GEMM ---------------------------------
// x_t[c][i][j] = sum_k a_t[c][i][k] * b_t[c][j][k]
__global__ __launch_bounds__(256) void k_tri(const u16* __restrict__ aT,
                                             const u16* __restrict__ bT,
                                             u16* __restrict__ xT) {
    __shared__ u16 sA[128 * PT];
    __shared__ u16 sB[128 * PT];
    int bid = blockIdx.x;
    // bijective XCD grouping (2048 % 8 == 0): each XCD gets 16 whole channels,
    // so a channel's 16 tiles reuse its 1 MB a/b panels inside one 4 MB L2.
    int swz = (bid & 7) * 256 + (bid >> 3);
    int c = swz >> 4;
    int i0 = ((swz >> 2) & 3) * 128, j0 = (swz & 3) * 128;
    const u16* aBase = aT + (long)c * NN + (long)i0 * N;
    const u16* bBase = bT + (long)c * NN + (long)j0 * N;
    int tid = threadIdx.x;
    int wave = tid >> 6, lane = tid & 63, lo = lane & 15, quad = lane >> 4;
    int mq = (wave >> 1) * 64, nq = (wave & 1) * 64;
    f32x4 acc[4][4];
#pragma unroll
    for (int mi = 0; mi < 4; ++mi)
#pragma unroll
        for (int ni = 0; ni < 4; ++ni) acc[mi][ni] = (f32x4)(0.f);

    int srow[2], sk[2];
#pragma unroll
    for (int p = 0; p < 2; ++p) {
        int linear = p * 2048 + tid * 8;
        srow[p] = linear >> 5; sk[p] = linear & 31;
    }
    uint4 ra[2], rb[2];
#pragma unroll
    for (int p = 0; p < 2; ++p) {
        ra[p] = *(const uint4*)(aBase + srow[p] * N + sk[p]);
        rb[p] = *(const uint4*)(bBase + srow[p] * N + sk[p]);
    }
    for (int kk = 0; kk < N; kk += 32) {
        __syncthreads();
#pragma unroll
        for (int p = 0; p < 2; ++p) {
            *(uint4*)(&sA[srow[p] * PT + sk[p]]) = ra[p];
            *(uint4*)(&sB[srow[p] * PT + sk[p]]) = rb[p];
        }
        __syncthreads();
        if (kk + 32 < N) {   // prefetch next slab; latency hides under MFMA
#pragma unroll
            for (int p = 0; p < 2; ++p) {
                ra[p] = *(const uint4*)(aBase + srow[p] * N + kk + 32 + sk[p]);
                rb[p] = *(const uint4*)(bBase + srow[p] * N + kk + 32 + sk[p]);
            }
        }
        bf16x8 af[4], bfr[4];
#pragma unroll
        for (int mi = 0; mi < 4; ++mi)
            af[mi] = *(const bf16x8*)(&sA[(mq + mi * 16 + lo) * PT + quad * 8]);
#pragma unroll
        for (int ni = 0; ni < 4; ++ni)
            bfr[ni] = *(const bf16x8*)(&sB[(nq + ni * 16 + lo) * PT + quad * 8]);
#pragma unroll
        for (int mi = 0; mi < 4; ++mi)
#pragma unroll
            for (int ni = 0; ni < 4; ++ni)
                acc[mi][ni] = __builtin_amdgcn_mfma_f32_16x16x32_bf16(af[mi], bfr[ni], acc[mi][ni], 0, 0, 0);
    }
    u16* outBase = xT + (long)c * NN;
#pragma unroll
    for (int mi = 0; mi < 4; ++mi)
#pragma unroll
        for (int ni = 0; ni < 4; ++ni)
#pragma unroll
            for (int r = 0; r < 4; ++r) {
                int gi = i0 + mq + mi * 16 + quad * 4 + r;
                int gj = j0 + nq + ni * 16 + lo;
                outBase[(long)gi * N + gj] = f2bf(acc[mi][ni][r]);
            }
}

// ------- K4: LN(x) @ w_z' + b_z', * gate -> out fp32 (ln_out folded) ---------
__global__ __launch_bounds__(256) void k_out(
    const u16* __restrict__ xT, const u16* __restrict__ gate,
    const u16* __restrict__ wzT, const float* __restrict__ bz,
    float* __restrict__ out) {
    __shared__ float sX[64 * PX];
    __shared__ u16 sA[64 * PK];
    __shared__ float sRed[2][4][64];
    __shared__ float2 sMV[64];
    long r0 = (long)blockIdx.x * 64;
    int tid = threadIdx.x;
#pragma unroll
    for (int p = 0; p < 4; ++p) {
        int linear = p * 2048 + tid * 8;
        int cc = linear >> 6, jr = linear & 63;
        uint4 v = *(const uint4*)(xT + (long)cc * NN + r0 + jr);
        u16* u = (u16*)&v;
#pragma unroll
        for (int e = 0; e < 8; ++e) sX[(jr + e) * PX + cc] = bf2f(u[e]);
    }
    __syncthreads();
    {
        int jr = tid & 63, part = tid >> 6;
        float s = 0, s2 = 0;
#pragma unroll
        for (int c = part * 32; c < part * 32 + 32; ++c) {
            float v = sX[jr * PX + c];
            s += v; s2 += v * v;
        }
        sRed[0][part][jr] = s; sRed[1][part][jr] = s2;
    }
    __syncthreads();
    if (tid < 64) {
        float S = 0, S2 = 0;
#pragma unroll
        for (int p = 0; p < 4; ++p) { S += sRed[0][p][tid]; S2 += sRed[1][p][tid]; }
        float mean = S * (1.f / 128.f);
        float var = S2 * (1.f / 128.f) - mean * mean;
        sMV[tid] = make_float2(mean, rsqrtf(var + 1e-5f));
    }
    __syncthreads();
    {
        int row = tid & 63, c0 = (tid >> 6) * 32;
        float2 mv = sMV[row];
#pragma unroll
        for (int c = c0; c < c0 + 32; ++c)
            sA[row * PK + c] = f2bf((sX[row * PX + c] - mv.x) * mv.y);
    }
    __syncthreads();
    int wave = tid >> 6, lane = tid & 63, lo = lane & 15, quad = lane >> 4;
    int msub = wave * 16;
    bf16x8 av[4];
#pragma unroll
    for (int ki = 0; ki < 4; ++ki)
        av[ki] = *(const bf16x8*)(&sA[(msub + lo) * PK + ki * 32 + quad * 8]);
    f32x4 acc[8];
#pragma unroll
    for (int nt = 0; nt < 8; ++nt) acc[nt] = (f32x4)(0.f);
#pragma unroll
    for (int nt = 0; nt < 8; ++nt)
#pragma unroll
        for (int ki = 0; ki < 4; ++ki) {
            bf16x8 b8 = *(const bf16x8*)(wzT + (nt * 16 + lo) * C + ki * 32 + quad * 8);
            acc[nt] = __builtin_amdgcn_mfma_f32_16x16x32_bf16(av[ki], b8, acc[nt], 0, 0, 0);
        }
#pragma unroll
    for (int nt = 0; nt < 8; ++nt) {
        int c = nt * 16 + lo;
        float bzv = bz[c];
#pragma unroll
        for (int r = 0; r < 4; ++r) {
            int row = msub + quad * 4 + r;
            long rr = r0 + row;
            float g = bf2f(gate[rr * C + c]);
            out[rr * C + c] = (acc[nt][r] + bzv) * g;
        }
    }
}

extern "C" void kernel_launch(void* const* d_in, const int* in_sizes, int n_in,
                              void* d_out, int out_size, void* d_ws, size_t ws_size,
                              hipStream_t stream) {
    const float* z       = (const float*)d_in[0];
    const float* mask    = (const float*)d_in[1];
    const float* w_ag    = (const float*)d_in[2];
    const float* b_ag    = (const float*)d_in[3];
    const float* w_ap    = (const float*)d_in[4];
    const float* b_ap    = (const float*)d_in[5];
    const float* w_bg    = (const float*)d_in[6];
    const float* b_bg    = (const float*)d_in[7];
    const float* w_bp    = (const float*)d_in[8];
    const float* b_bp    = (const float*)d_in[9];
    const float* w_g     = (const float*)d_in[10];
    const float* b_g     = (const float*)d_in[11];
    const float* w_z     = (const float*)d_in[12];
    const float* b_z     = (const float*)d_in[13];
    const float* ln_in_g = (const float*)d_in[14];
    const float* ln_in_b = (const float*)d_in[15];
    const float* ln_out_g= (const float*)d_in[16];
    const float* ln_out_b= (const float*)d_in[17];
    float* out = (float*)d_out;

    char* ws = (char*)d_ws;
    u16* a_t  = (u16*)(ws);                          // 64 MB
    u16* b_t  = (u16*)(ws + 67108864L);              // 64 MB
    u16* gate = (u16*)(ws + 134217728L);             // 64 MB
    u16* x_t  = (u16*)(ws + 201326592L);             // 64 MB
    u16* wag_t = (u16*)(ws + 268435456L);
    u16* wap_t = wag_t + 16384;
    u16* wbg_t = wag_t + 32768;
    u16* wbp_t = wag_t + 49152;
    u16* wg_t  = wag_t + 65536;
    u16* wz_t  = wag_t + 81920;
    float* biasAdj = (float*)(ws + 268435456L + 196608L);   // 6*128 fp32

    k_wt_all<<<384, 256, 0, stream>>>(w_ag, w_ap, w_bg, w_bp, w_g, w_z,
                                      ln_in_g, ln_out_g,
                                      wag_t, wap_t, wbg_t, wbp_t, wg_t, wz_t);

    k_bias<<<3, 256, 0, stream>>>(w_ag, w_ap, w_bg, w_bp, w_g, w_z,
                                  b_ag, b_ap, b_bg, b_bp, b_g, b_z,
                                  ln_in_b, ln_out_b, biasAdj);

    k_proj_fused<<<NN / 64, 256, 0, stream>>>(
        z, mask, wag_t, wap_t, wbg_t, wbp_t, wg_t, biasAdj,
        a_t, b_t, gate);

    k_tri<<<2048, 256, 0, stream>>>(a_t, b_t, x_t);

    k_out<<<NN / 64, 256, 0, stream>>>(x_t, gate, wz_t, biasAdj + 640, out);
}